// Round 6
// baseline (173.329 us; speedup 1.0000x reference)
//
#include <hip/hip_runtime.h>
#include <math.h>

#define EMBED_DIM 64
#define NUM_EXPERTS 4
#define LANES 64
#define TOKS 64                    // tokens per tile (1 per lane)
#define TILE_CHUNKS (TOKS * 16)    // 1024 float4 = 16 KB per tile
#define NBLOCKS 1280               // 5 per CU (LDS-limited: 2x16KB buffers)

// Persistent SINGLE-WAVE blocks, depth-2 software pipeline with counted
// vmcnt (no __syncthreads anywhere -> no vmcnt(0) barrier drain in the
// main loop). Each wave owns a 2x16KB LDS double buffer: issue tile t+1's
// 16 global_load_lds (1KB each, fully coalesced), s_waitcnt vmcnt(16) to
// retire only tile t's loads, compute, store, flip parity.
// vmcnt ledger (retires in issue order): [loads(t):16][stores(t-1):2]
// [loads(t+1):16] -> vmcnt(16) == tile t ready. Last iter: vmcnt(0).
//
// Arithmetic is bit-identical to the passing kernel: strictly sequential
// f32 mul-then-add chain per logit (no FMA contraction), matching numpy
// einsum's sum-of-products order. LDS uses the proven XOR chunk swizzle on
// BOTH sides (inverse-swizzled global source + swizzled ds_read) so the
// 256B-stride row reads are bank-conflict-free.
__global__ __launch_bounds__(LANES) void gate_kernel(
    const float* __restrict__ x,
    const float* __restrict__ W,
    float* __restrict__ wout,     // [n,4] dense routing weights
    float* __restrict__ iout,     // [n,2] top-k indices, stored as float
    int n)
{
#pragma clang fp contract(off)
    __shared__ float4 lds[2 * TILE_CHUNKS];

    const int lane   = threadIdx.x;          // 0..63, tile-local token id
    const int ntiles = n / TOKS;             // 32768
    const int stride = gridDim.x;

    const float4* x4 = reinterpret_cast<const float4*>(x);
    const float4* W4 = reinterpret_cast<const float4*>(W);

    // Hoist W into SSA locals (fully unrolled -> registers), so the asm
    // "memory" clobbers below can't force per-tile reloads.
    float4 wA[16], wB[16], wC[16], wD[16];
    #pragma unroll
    for (int j = 0; j < 16; ++j) {
        wA[j] = W4[ 0 + j];
        wB[j] = W4[16 + j];
        wC[j] = W4[32 + j];
        wD[j] = W4[48 + j];
    }

    // Issue one tile's staging loads: linear LDS dest chunk L=i*64+lane,
    // global source chunk gc = (tk<<4)|(c^(tk&7)) (inverse XOR swizzle).
    auto issue = [&](int tile, int parity) {
        const size_t tileChunk = (size_t)tile * TILE_CHUNKS;
        #pragma unroll
        for (int i = 0; i < 16; ++i) {
            const int L  = i * 64 + lane;
            const int tk = L >> 4;
            const int c  = L & 15;
            const int gc = (tk << 4) | (c ^ (tk & 7));
            __builtin_amdgcn_global_load_lds(
                (const __attribute__((address_space(1))) void*)(x4 + tileChunk + gc),
                (__attribute__((address_space(3))) void*)&lds[parity * TILE_CHUNKS + i * 64],
                16, 0, 0);
        }
    };

    int t = blockIdx.x;
    if (t >= ntiles) return;

    issue(t, 0);
    int parity = 0;

    for (; t < ntiles; t += stride) {
        const int tn = t + stride;
        const bool hasnext = (tn < ntiles);
        if (hasnext) issue(tn, parity ^ 1);

        if (hasnext) { asm volatile("s_waitcnt vmcnt(16)" ::: "memory"); }
        else         { asm volatile("s_waitcnt vmcnt(0)"  ::: "memory"); }
        __builtin_amdgcn_sched_barrier(0);

        const float4* xt = &lds[parity * TILE_CHUNKS];

        float s0 = 0.0f, s1 = 0.0f, s2 = 0.0f, s3 = 0.0f;
        #pragma unroll
        for (int j = 0; j < 16; ++j) {
            const float4 xv = xt[(lane << 4) | (j ^ (lane & 7))];
            const float4 a = wA[j];
            const float4 b = wB[j];
            const float4 c = wC[j];
            const float4 d = wD[j];
            // strict d-order, mul rounded then add rounded (no contraction):
            s0 = s0 + xv.x * a.x; s0 = s0 + xv.y * a.y;
            s0 = s0 + xv.z * a.z; s0 = s0 + xv.w * a.w;
            s1 = s1 + xv.x * b.x; s1 = s1 + xv.y * b.y;
            s1 = s1 + xv.z * b.z; s1 = s1 + xv.w * b.w;
            s2 = s2 + xv.x * c.x; s2 = s2 + xv.y * c.y;
            s2 = s2 + xv.z * c.z; s2 = s2 + xv.w * c.w;
            s3 = s3 + xv.x * d.x; s3 = s3 + xv.y * d.y;
            s3 = s3 + xv.z * d.z; s3 = s3 + xv.w * d.w;
        }

        // top-1: strict > -> ties to LOWER index (lax.top_k semantics).
        int   i1 = 0;  float v1 = s0;
        if (s1 > v1) { v1 = s1; i1 = 1; }
        if (s2 > v1) { v1 = s2; i1 = 2; }
        if (s3 > v1) { v1 = s3; i1 = 3; }
        int   i2 = -1; float v2 = -INFINITY;
        if (i1 != 0 && s0 > v2) { v2 = s0; i2 = 0; }
        if (i1 != 1 && s1 > v2) { v2 = s1; i2 = 1; }
        if (i1 != 2 && s2 > v2) { v2 = s2; i2 = 2; }
        if (i1 != 3 && s3 > v2) { v2 = s3; i2 = 3; }

        const float e2  = expf(v2 - v1);
        const float den = 1.0f + e2;
        const float p1  = 1.0f / den;
        const float p2  = e2 / den;

        const int tok = t * TOKS + lane;

        float4 wv;
        wv.x = (i1 == 0) ? p1 : ((i2 == 0) ? p2 : 0.0f);
        wv.y = (i1 == 1) ? p1 : ((i2 == 1) ? p2 : 0.0f);
        wv.z = (i1 == 2) ? p1 : ((i2 == 2) ? p2 : 0.0f);
        wv.w = (i1 == 3) ? p1 : ((i2 == 3) ? p2 : 0.0f);
        reinterpret_cast<float4*>(wout)[tok] = wv;

        float2 iv;
        iv.x = (float)i1;
        iv.y = (float)i2;
        reinterpret_cast<float2*>(iout)[tok] = iv;

        parity ^= 1;
    }
}

extern "C" void kernel_launch(void* const* d_in, const int* in_sizes, int n_in,
                              void* d_out, int out_size, void* d_ws, size_t ws_size,
                              hipStream_t stream) {
    const float* x = (const float*)d_in[0];
    const float* W = (const float*)d_in[1];
    const int n = in_sizes[0] / EMBED_DIM;   // 2097152

    float* wout = (float*)d_out;                    // n*4 floats
    float* iout = wout + (size_t)n * NUM_EXPERTS;   // n*2 indices stored as float

    hipLaunchKernelGGL(gate_kernel, dim3(NBLOCKS), dim3(LANES), 0, stream,
                       x, W, wout, iout, n);
}

// Round 7
// 127.735 us; speedup vs baseline: 1.3569x; 1.3569x over previous
//
#include <hip/hip_runtime.h>
#include <math.h>

#define EMBED_DIM 64
#define NUM_EXPERTS 4
#define THREADS 128                 // 2 independent waves per block
#define TILE_CHUNKS 1024            // 64 tokens * 16 float4 = 16 KB per wave
#define NBLOCKS 1280                // 5 blocks/CU (32 KB LDS each) -> 10 waves/CU

// Persistent blocks; each WAVE is an independent worker with its own 16 KB
// LDS tile buffer. No __syncthreads anywhere. Per tile: issue 16 perfectly
// coalesced 1KB global_load_lds, wait own vmcnt(0), compute, store. The 10
// waves/CU each holding 16 outstanding KB of loads keep HBM saturated while
// other waves compute (queue depth, not double buffering, is what feeds BW).
// W is re-read per tile via uniform loads (s_load / constant cache — proven
// free in round 5); NO register hoisting (round 6's 256-VGPR mistake).
//
// Arithmetic is bit-identical to the passing kernels: strictly sequential
// f32 mul-then-add chain per logit (no FMA contraction; pragma disables
// -ffp-contract=fast), matching numpy einsum's sum-of-products order.
// LDS XOR chunk swizzle on BOTH sides (inverse-swizzled global source +
// swizzled ds_read) keeps the 256B-stride row reads bank-conflict-free.
__global__ __launch_bounds__(THREADS) void gate_kernel(
    const float* __restrict__ x,
    const float* __restrict__ W,
    float* __restrict__ wout,     // [n,4] dense routing weights
    float* __restrict__ iout,     // [n,2] top-k indices, stored as float
    int n)
{
#pragma clang fp contract(off)
    __shared__ float4 lds[2 * TILE_CHUNKS];   // one 16KB tile per wave

    const int lane = threadIdx.x & 63;
    const int wid  = threadIdx.x >> 6;              // wave in block: 0/1
    const int gw   = blockIdx.x * 2 + wid;          // global wave id
    const int nw   = NBLOCKS * 2;                   // 2560 worker waves
    const int ntiles = n / 64;                      // 32768

    const float4* x4 = reinterpret_cast<const float4*>(x);
    const float4* W4 = reinterpret_cast<const float4*>(W);
    float4* tilebuf = &lds[wid * TILE_CHUNKS];

    for (int t = gw; t < ntiles; t += nw) {
        const size_t tileChunk = (size_t)t * TILE_CHUNKS;

        // Stage 64 rows (16 KB), fully coalesced: linear LDS dest chunk
        // L = i*64+lane; global source chunk gc = (tk<<4)|(c^(tk&7))
        // (inverse XOR swizzle; read side applies the same XOR).
        #pragma unroll
        for (int i = 0; i < 16; ++i) {
            const int L  = i * 64 + lane;
            const int tk = L >> 4;
            const int c  = L & 15;
            const int gc = (tk << 4) | (c ^ (tk & 7));
            __builtin_amdgcn_global_load_lds(
                (const __attribute__((address_space(1))) void*)(x4 + tileChunk + gc),
                (__attribute__((address_space(3))) void*)&tilebuf[i * 64],
                16, 0, 0);
        }
        asm volatile("s_waitcnt vmcnt(0)" ::: "memory");
        __builtin_amdgcn_sched_barrier(0);

        float s0 = 0.0f, s1 = 0.0f, s2 = 0.0f, s3 = 0.0f;
        #pragma unroll
        for (int j = 0; j < 16; ++j) {
            const float4 xv = tilebuf[(lane << 4) | (j ^ (lane & 7))];
            const float4 a = W4[ 0 + j];
            const float4 b = W4[16 + j];
            const float4 c = W4[32 + j];
            const float4 d = W4[48 + j];
            // strict d-order, mul rounded then add rounded (no contraction):
            s0 = s0 + xv.x * a.x; s0 = s0 + xv.y * a.y;
            s0 = s0 + xv.z * a.z; s0 = s0 + xv.w * a.w;
            s1 = s1 + xv.x * b.x; s1 = s1 + xv.y * b.y;
            s1 = s1 + xv.z * b.z; s1 = s1 + xv.w * b.w;
            s2 = s2 + xv.x * c.x; s2 = s2 + xv.y * c.y;
            s2 = s2 + xv.z * c.z; s2 = s2 + xv.w * c.w;
            s3 = s3 + xv.x * d.x; s3 = s3 + xv.y * d.y;
            s3 = s3 + xv.z * d.z; s3 = s3 + xv.w * d.w;
        }

        // top-1: strict > -> ties to LOWER index (lax.top_k semantics).
        int   i1 = 0;  float v1 = s0;
        if (s1 > v1) { v1 = s1; i1 = 1; }
        if (s2 > v1) { v1 = s2; i1 = 2; }
        if (s3 > v1) { v1 = s3; i1 = 3; }
        int   i2 = -1; float v2 = -INFINITY;
        if (i1 != 0 && s0 > v2) { v2 = s0; i2 = 0; }
        if (i1 != 1 && s1 > v2) { v2 = s1; i2 = 1; }
        if (i1 != 2 && s2 > v2) { v2 = s2; i2 = 2; }
        if (i1 != 3 && s3 > v2) { v2 = s3; i2 = 3; }

        const float e2  = expf(v2 - v1);
        const float den = 1.0f + e2;
        const float p1  = 1.0f / den;
        const float p2  = e2 / den;

        const int tok = t * 64 + lane;

        float4 wv;
        wv.x = (i1 == 0) ? p1 : ((i2 == 0) ? p2 : 0.0f);
        wv.y = (i1 == 1) ? p1 : ((i2 == 1) ? p2 : 0.0f);
        wv.z = (i1 == 2) ? p1 : ((i2 == 2) ? p2 : 0.0f);
        wv.w = (i1 == 3) ? p1 : ((i2 == 3) ? p2 : 0.0f);
        reinterpret_cast<float4*>(wout)[tok] = wv;

        float2 iv;
        iv.x = (float)i1;
        iv.y = (float)i2;
        reinterpret_cast<float2*>(iout)[tok] = iv;
    }
}

extern "C" void kernel_launch(void* const* d_in, const int* in_sizes, int n_in,
                              void* d_out, int out_size, void* d_ws, size_t ws_size,
                              hipStream_t stream) {
    const float* x = (const float*)d_in[0];
    const float* W = (const float*)d_in[1];
    const int n = in_sizes[0] / EMBED_DIM;   // 2097152

    float* wout = (float*)d_out;                    // n*4 floats
    float* iout = wout + (size_t)n * NUM_EXPERTS;   // n*2 indices stored as float

    hipLaunchKernelGGL(gate_kernel, dim3(NBLOCKS), dim3(THREADS), 0, stream,
                       x, W, wout, iout, n);
}